// Round 4
// baseline (173.875 us; speedup 1.0000x reference)
//
#include <hip/hip_runtime.h>
#include <hip/hip_bf16.h>
#include <math.h>

typedef unsigned short u16;
typedef __attribute__((ext_vector_type(8))) short short8;   // 8 bf16 (4 VGPRs)
typedef __attribute__((ext_vector_type(4))) float f32x4;

#define NB 8192
#define ND 64
// dist scale: S = exp(-dist/0.05) = exp2(-K*dist), K = 20/ln2
// We carry K^2 inside d2 so that S = exp2(-sqrt(K2*d2)).
#define K2     832.5475634f      // (20/ln2)^2
#define M2K2  -1665.0951268f     // -2*K2
#define LN2    0.69314718055994531f

// S from pre-scaled squared distance (d2K = K2 * dist^2)
__device__ __forceinline__ float simval2(float d2K) {
    return __builtin_amdgcn_exp2f(-__builtin_amdgcn_sqrtf(fmaxf(d2K, 0.0f)));
}

// ---------------- prep: bf16 convert, K2-scaled norms, diagS, zero accums ---
__global__ __launch_bounds__(256) void snn_prep(
    const float* __restrict__ text, const float* __restrict__ image,
    u16* __restrict__ textBf, u16* __restrict__ imageBf,
    float* __restrict__ normT, float* __restrict__ normI,
    float* __restrict__ diagS, float* __restrict__ sameSum,
    float* __restrict__ totSum, float* __restrict__ out)
{
    const int lane = threadIdx.x & 63;
    const int row  = blockIdx.x * 4 + (threadIdx.x >> 6);
    const int idx  = row * ND + lane;

    float t  = text[idx];
    float im = image[idx];
    __hip_bfloat16 tb = __float2bfloat16(t);
    __hip_bfloat16 ib = __float2bfloat16(im);
    u16 tbits, ibits;
    __builtin_memcpy(&tbits, &tb, 2);
    __builtin_memcpy(&ibits, &ib, 2);
    textBf[idx]  = tbits;
    imageBf[idx] = ibits;

    float nt = t * t;
    float ni = im * im;
    float dp = __bfloat162float(tb) * __bfloat162float(ib); // match MFMA path
    #pragma unroll
    for (int m = 32; m >= 1; m >>= 1) {
        nt += __shfl_xor(nt, m, 64);
        ni += __shfl_xor(ni, m, 64);
        dp += __shfl_xor(dp, m, 64);
    }
    if (lane == 0) {
        float snt = K2 * nt;
        float sni = K2 * ni;
        normT[row] = snt;
        normI[row] = sni;
        float d2K = fmaf(M2K2, dp, sni + snt);  // K2 * dist(image_r, text_r)^2
        diagS[row] = simval2(d2K);
        sameSum[row] = 0.0f;
        totSum[row]  = 0.0f;
        if (row == 0) out[0] = 0.0f;
    }
}

// ---------------- main: fused pairwise S + grouped row sums -----------------
// Grid: (64 row-tiles, 32 col-chunks). Block: 256 thr = 4 waves.
// Block tile: 128 rows x 256 cols (2 col-tiles of 128). Wave: 32 rows.
__global__ __launch_bounds__(256, 4) void snn_main(
    const u16* __restrict__ textBf, const u16* __restrict__ imageBf,
    const float* __restrict__ normT, const float* __restrict__ normI,
    const int* __restrict__ groups,
    float* __restrict__ sameSum, float* __restrict__ totSum)
{
    const int lane = threadIdx.x & 63;
    const int w    = threadIdx.x >> 6;
    const int g    = lane >> 4;      // 16-lane group id (0..3)
    const int l15  = lane & 15;
    const int rowBase  = blockIdx.x * 128 + w * 32;
    const int colChunk = blockIdx.y * 256;

    // A fragments (image rows), resident for the whole block
    short8 aFrag[2][2];
    #pragma unroll
    for (int m = 0; m < 2; ++m)
        #pragma unroll
        for (int kk = 0; kk < 2; ++kk)
            aFrag[m][kk] = *(const short8*)(imageBf +
                (rowBase + m * 16 + l15) * ND + kk * 32 + g * 8);

    // per-thread row metadata: row(m,r) = rowBase + m*16 + g*4 + r
    float nI[2][4];
    int   gI[2][4];
    #pragma unroll
    for (int m = 0; m < 2; ++m)
        #pragma unroll
        for (int r = 0; r < 4; ++r) {
            int row = rowBase + m * 16 + g * 4 + r;
            nI[m][r] = normI[row];
            gI[m][r] = groups[row];
        }

    float sameAcc[2][4];
    float totAcc[2][4];
    #pragma unroll
    for (int m = 0; m < 2; ++m)
        #pragma unroll
        for (int r = 0; r < 4; ++r) { sameAcc[m][r] = 0.0f; totAcc[m][r] = 0.0f; }

    #pragma unroll
    for (int ct = 0; ct < 2; ++ct) {
        const int colBase = colChunk + ct * 128;

        float nT[8];
        int   gJ[8];
        f32x4 acc[2][8];
        #pragma unroll
        for (int n = 0; n < 8; ++n) {
            const int col = colBase + n * 16 + l15;
            nT[n] = normT[col];
            gJ[n] = groups[col];
            short8 b0 = *(const short8*)(textBf + col * ND + g * 8);
            short8 b1 = *(const short8*)(textBf + col * ND + 32 + g * 8);
            #pragma unroll
            for (int m = 0; m < 2; ++m) {
                acc[m][n] = f32x4{0.f, 0.f, 0.f, 0.f};
                acc[m][n] = __builtin_amdgcn_mfma_f32_16x16x32_bf16(
                                aFrag[m][0], b0, acc[m][n], 0, 0, 0);
                acc[m][n] = __builtin_amdgcn_mfma_f32_16x16x32_bf16(
                                aFrag[m][1], b1, acc[m][n], 0, 0, 0);
            }
        }

        // epilogue: d2K -> S -> predicated row accumulation
        #pragma unroll
        for (int m = 0; m < 2; ++m)
            #pragma unroll
            for (int n = 0; n < 8; ++n) {
                f32x4 c = acc[m][n];
                #pragma unroll
                for (int r = 0; r < 4; ++r) {
                    float d2K = fmaf(M2K2, c[r], nI[m][r] + nT[n]);
                    float s   = simval2(d2K);
                    totAcc[m][r] += s;
                    sameAcc[m][r] += (gI[m][r] == gJ[n]) ? s : 0.0f;
                }
            }
    }

    // reduce across the 16 lanes sharing each row, then one atomic per row
    #pragma unroll
    for (int m = 0; m < 2; ++m)
        #pragma unroll
        for (int r = 0; r < 4; ++r) {
            float sv = sameAcc[m][r];
            float tv = totAcc[m][r];
            #pragma unroll
            for (int mk = 8; mk >= 1; mk >>= 1) {
                sv += __shfl_xor(sv, mk, 64);
                tv += __shfl_xor(tv, mk, 64);
            }
            if (l15 == 0) {
                int row = rowBase + m * 16 + g * 4 + r;
                atomicAdd(&sameSum[row], sv);
                atomicAdd(&totSum[row], tv);
            }
        }
}

// ---------------- finalize: per-row loss + scalar reduction -----------------
__global__ __launch_bounds__(256) void snn_finalize(
    const float* __restrict__ sameSum, const float* __restrict__ totSum,
    const float* __restrict__ diagS, const int* __restrict__ groups,
    float* __restrict__ out)
{
    const int i = blockIdx.x * 256 + threadIdx.x;
    float sameS = sameSum[i];
    float tot   = totSum[i];
    float diag  = diagS[i];
    float A = sameS - diag;            // same-group sum, j != i
    int g0 = groups[0];
    bool cond = (groups[i] == g0) && (i != 0);
    float num = cond ? A : (A + sameS);   // F == sameS
    float den = tot - sameS;
    bool valid = (num != 0.0f) && (den != 0.0f);
    float ratio = (valid ? num : 1.0f) / (valid ? den : 1.0f);
    float per = valid ? (-LN2 * __builtin_amdgcn_logf(ratio)) : 0.0f;

    float v = per;
    #pragma unroll
    for (int mk = 32; mk >= 1; mk >>= 1) v += __shfl_xor(v, mk, 64);
    __shared__ float wsum[4];
    if ((threadIdx.x & 63) == 0) wsum[threadIdx.x >> 6] = v;
    __syncthreads();
    if (threadIdx.x == 0) {
        float s = wsum[0] + wsum[1] + wsum[2] + wsum[3];
        atomicAdd(out, s * (1.0f / 8192.0f));
    }
}

// ---------------- launch ----------------------------------------------------
extern "C" void kernel_launch(void* const* d_in, const int* in_sizes, int n_in,
                              void* d_out, int out_size, void* d_ws, size_t ws_size,
                              hipStream_t stream) {
    const float* text  = (const float*)d_in[0];
    const float* image = (const float*)d_in[1];
    const int*   groups = (const int*)d_in[2];
    float* out = (float*)d_out;

    char* ws = (char*)d_ws;
    u16* textBf  = (u16*)ws;                          // 1 MB
    u16* imageBf = (u16*)(ws + (1 << 20));            // 1 MB
    float* normT   = (float*)(ws + (2 << 20));        // 32 KB each
    float* normI   = normT + NB;
    float* diagS   = normI + NB;
    float* sameSum = diagS + NB;
    float* totSum  = sameSum + NB;

    snn_prep<<<NB / 4, 256, 0, stream>>>(text, image, textBf, imageBf,
                                         normT, normI, diagS, sameSum, totSum, out);
    snn_main<<<dim3(64, 32), 256, 0, stream>>>(textBf, imageBf, normT, normI,
                                               groups, sameSum, totSum);
    snn_finalize<<<NB / 256, 256, 0, stream>>>(sameSum, totSum, diagS, groups, out);
}

// Round 5
// 109.729 us; speedup vs baseline: 1.5846x; 1.5846x over previous
//
#include <hip/hip_runtime.h>
#include <hip/hip_bf16.h>
#include <math.h>

typedef unsigned short u16;
typedef __attribute__((ext_vector_type(8))) short short8;   // 8 bf16 (4 VGPRs)
typedef __attribute__((ext_vector_type(4))) float f32x4;

#define NB 8192
#define ND 64
// dist scale: S = exp(-dist/0.05) = exp2(-K*dist), K = 20/ln2
// We carry K^2 inside d2 so that S = exp2(-sqrt(K2*d2)).
#define K2     832.5475634f      // (20/ln2)^2
#define M2K2  -1665.0951268f     // -2*K2
#define LN2    0.69314718055994531f

// S from pre-scaled squared distance (d2K = K2 * dist^2)
__device__ __forceinline__ float simval2(float d2K) {
    return __builtin_amdgcn_exp2f(-__builtin_amdgcn_sqrtf(fmaxf(d2K, 0.0f)));
}

// ---------------- prep: bf16 convert, K2-scaled norms, diagS, zero accums ---
__global__ __launch_bounds__(256) void snn_prep(
    const float* __restrict__ text, const float* __restrict__ image,
    u16* __restrict__ textBf, u16* __restrict__ imageBf,
    float* __restrict__ normT, float* __restrict__ normI,
    float* __restrict__ diagS, float* __restrict__ sameSum,
    float* __restrict__ totSum, float* __restrict__ out)
{
    const int lane = threadIdx.x & 63;
    const int row  = blockIdx.x * 4 + (threadIdx.x >> 6);
    const int idx  = row * ND + lane;

    float t  = text[idx];
    float im = image[idx];
    __hip_bfloat16 tb = __float2bfloat16(t);
    __hip_bfloat16 ib = __float2bfloat16(im);
    u16 tbits, ibits;
    __builtin_memcpy(&tbits, &tb, 2);
    __builtin_memcpy(&ibits, &ib, 2);
    textBf[idx]  = tbits;
    imageBf[idx] = ibits;

    float nt = t * t;
    float ni = im * im;
    float dp = __bfloat162float(tb) * __bfloat162float(ib); // match MFMA path
    #pragma unroll
    for (int m = 32; m >= 1; m >>= 1) {
        nt += __shfl_xor(nt, m, 64);
        ni += __shfl_xor(ni, m, 64);
        dp += __shfl_xor(dp, m, 64);
    }
    if (lane == 0) {
        float snt = K2 * nt;
        float sni = K2 * ni;
        normT[row] = snt;
        normI[row] = sni;
        float d2K = fmaf(M2K2, dp, sni + snt);  // K2 * dist(image_r, text_r)^2
        diagS[row] = simval2(d2K);
        sameSum[row] = 0.0f;
        totSum[row]  = 0.0f;
        if (row == 0) out[0] = 0.0f;
    }
}

// ---------------- main: fused pairwise S + grouped row sums -----------------
// Grid: (64 row-tiles, 32 col-chunks). Block: 256 thr = 4 waves.
// Block tile: 128 rows x 256 cols (2 col-tiles of 128). Wave: 32 rows.
// NOTE: gfx950 unified VGPR/AGPR file — min-waves=4 caps combined regs at 128
// and SPILLS the 64-reg accumulator (R1: 365 MB scratch traffic, 115 µs).
// min-waves=2 (256-reg budget) is the proven no-spill point (R0: VGPR 84).
__global__ __launch_bounds__(256, 2) void snn_main(
    const u16* __restrict__ textBf, const u16* __restrict__ imageBf,
    const float* __restrict__ normT, const float* __restrict__ normI,
    const int* __restrict__ groups,
    float* __restrict__ sameSum, float* __restrict__ totSum)
{
    const int lane = threadIdx.x & 63;
    const int w    = threadIdx.x >> 6;
    const int g    = lane >> 4;      // 16-lane group id (0..3)
    const int l15  = lane & 15;
    const int rowBase  = blockIdx.x * 128 + w * 32;
    const int colChunk = blockIdx.y * 256;

    // A fragments (image rows), resident for the whole block
    short8 aFrag[2][2];
    #pragma unroll
    for (int m = 0; m < 2; ++m)
        #pragma unroll
        for (int kk = 0; kk < 2; ++kk)
            aFrag[m][kk] = *(const short8*)(imageBf +
                (rowBase + m * 16 + l15) * ND + kk * 32 + g * 8);

    // per-thread row metadata: row(m,r) = rowBase + m*16 + g*4 + r
    float nI[2][4];
    int   gI[2][4];
    #pragma unroll
    for (int m = 0; m < 2; ++m)
        #pragma unroll
        for (int r = 0; r < 4; ++r) {
            int row = rowBase + m * 16 + g * 4 + r;
            nI[m][r] = normI[row];
            gI[m][r] = groups[row];
        }

    float sameAcc[2][4];
    float totAcc[2][4];
    #pragma unroll
    for (int m = 0; m < 2; ++m)
        #pragma unroll
        for (int r = 0; r < 4; ++r) { sameAcc[m][r] = 0.0f; totAcc[m][r] = 0.0f; }

    #pragma unroll
    for (int ct = 0; ct < 2; ++ct) {
        const int colBase = colChunk + ct * 128;

        float nT[8];
        int   gJ[8];
        f32x4 acc[2][8];
        #pragma unroll
        for (int n = 0; n < 8; ++n) {
            const int col = colBase + n * 16 + l15;
            nT[n] = normT[col];
            gJ[n] = groups[col];
            short8 b0 = *(const short8*)(textBf + col * ND + g * 8);
            short8 b1 = *(const short8*)(textBf + col * ND + 32 + g * 8);
            #pragma unroll
            for (int m = 0; m < 2; ++m) {
                acc[m][n] = f32x4{0.f, 0.f, 0.f, 0.f};
                acc[m][n] = __builtin_amdgcn_mfma_f32_16x16x32_bf16(
                                aFrag[m][0], b0, acc[m][n], 0, 0, 0);
                acc[m][n] = __builtin_amdgcn_mfma_f32_16x16x32_bf16(
                                aFrag[m][1], b1, acc[m][n], 0, 0, 0);
            }
        }

        // epilogue: d2K -> S -> predicated row accumulation
        #pragma unroll
        for (int m = 0; m < 2; ++m)
            #pragma unroll
            for (int n = 0; n < 8; ++n) {
                f32x4 c = acc[m][n];
                #pragma unroll
                for (int r = 0; r < 4; ++r) {
                    float d2K = fmaf(M2K2, c[r], nI[m][r] + nT[n]);
                    float s   = simval2(d2K);
                    totAcc[m][r] += s;
                    sameAcc[m][r] += (gI[m][r] == gJ[n]) ? s : 0.0f;
                }
            }
    }

    // reduce across the 16 lanes sharing each row, then one atomic per row
    #pragma unroll
    for (int m = 0; m < 2; ++m)
        #pragma unroll
        for (int r = 0; r < 4; ++r) {
            float sv = sameAcc[m][r];
            float tv = totAcc[m][r];
            #pragma unroll
            for (int mk = 8; mk >= 1; mk >>= 1) {
                sv += __shfl_xor(sv, mk, 64);
                tv += __shfl_xor(tv, mk, 64);
            }
            if (l15 == 0) {
                int row = rowBase + m * 16 + g * 4 + r;
                atomicAdd(&sameSum[row], sv);
                atomicAdd(&totSum[row], tv);
            }
        }
}

// ---------------- finalize: per-row loss + scalar reduction -----------------
__global__ __launch_bounds__(256) void snn_finalize(
    const float* __restrict__ sameSum, const float* __restrict__ totSum,
    const float* __restrict__ diagS, const int* __restrict__ groups,
    float* __restrict__ out)
{
    const int i = blockIdx.x * 256 + threadIdx.x;
    float sameS = sameSum[i];
    float tot   = totSum[i];
    float diag  = diagS[i];
    float A = sameS - diag;            // same-group sum, j != i
    int g0 = groups[0];
    bool cond = (groups[i] == g0) && (i != 0);
    float num = cond ? A : (A + sameS);   // F == sameS
    float den = tot - sameS;
    bool valid = (num != 0.0f) && (den != 0.0f);
    float ratio = (valid ? num : 1.0f) / (valid ? den : 1.0f);
    float per = valid ? (-LN2 * __builtin_amdgcn_logf(ratio)) : 0.0f;

    float v = per;
    #pragma unroll
    for (int mk = 32; mk >= 1; mk >>= 1) v += __shfl_xor(v, mk, 64);
    __shared__ float wsum[4];
    if ((threadIdx.x & 63) == 0) wsum[threadIdx.x >> 6] = v;
    __syncthreads();
    if (threadIdx.x == 0) {
        float s = wsum[0] + wsum[1] + wsum[2] + wsum[3];
        atomicAdd(out, s * (1.0f / 8192.0f));
    }
}

// ---------------- launch ----------------------------------------------------
extern "C" void kernel_launch(void* const* d_in, const int* in_sizes, int n_in,
                              void* d_out, int out_size, void* d_ws, size_t ws_size,
                              hipStream_t stream) {
    const float* text  = (const float*)d_in[0];
    const float* image = (const float*)d_in[1];
    const int*   groups = (const int*)d_in[2];
    float* out = (float*)d_out;

    char* ws = (char*)d_ws;
    u16* textBf  = (u16*)ws;                          // 1 MB
    u16* imageBf = (u16*)(ws + (1 << 20));            // 1 MB
    float* normT   = (float*)(ws + (2 << 20));        // 32 KB each
    float* normI   = normT + NB;
    float* diagS   = normI + NB;
    float* sameSum = diagS + NB;
    float* totSum  = sameSum + NB;

    snn_prep<<<NB / 4, 256, 0, stream>>>(text, image, textBf, imageBf,
                                         normT, normI, diagS, sameSum, totSum, out);
    snn_main<<<dim3(64, 32), 256, 0, stream>>>(textBf, imageBf, normT, normI,
                                               groups, sameSum, totSum);
    snn_finalize<<<NB / 256, 256, 0, stream>>>(sameSum, totSum, diagS, groups, out);
}